// Round 6
// baseline (327.397 us; speedup 1.0000x reference)
//
#include <hip/hip_runtime.h>

// out[b,n] = sum_e c[b,n,e] * s[b,e];  B=32, N=8192, E=256, fp32.
// R5 lesson: reverse sweep neutral -> c is NOT L3-resident at kernel start.
// Working model: harness's 1GB ws-poison fill runs last, leaving L3 full of
// DIRTY poison lines. NT's +27us win over plain = avoided evicting those
// dirty lines (no writeback traffic during our reads), not avoided misses.
// R6 single change vs R3: 2048 blocks (32 waves/CU) with NT held fixed —
// the occupancy axis was never tested with NT (R4 changed both variables).
// Deeper wave pool to hide the ~900cyc HBM wait + ~300cyc shuffle tail.

typedef float f32x4 __attribute__((ext_vector_type(4)));

constexpr int kLogN        = 13;   // N = 8192 rows per batch
constexpr int kF4PerRow    = 64;   // E/4
constexpr int kRowsPerIter = 8;    // rows per wave per grid-stride step
constexpr int kBlocks      = 2048; // 8 blocks/CU -> 32 waves/CU
constexpr int kThreads     = 256;  // 4 waves/block -> 8192 waves

__device__ __forceinline__ float lane_merge(float a, float b, int sel, int off) {
    float send = sel ? a : b;
    float recv = __shfl_xor(send, off, 64);
    return (sel ? b : a) + recv;
}

__global__ __launch_bounds__(kThreads) void ctx_seg_score_kernel(
    const float* __restrict__ c,   // [B*N, E]
    const float* __restrict__ s,   // [B, E]
    float* __restrict__ out,       // [B*N]
    int total_rows)                // B*N = 262144
{
    const int lane   = threadIdx.x & 63;
    const int gwave  = (blockIdx.x * blockDim.x + threadIdx.x) >> 6;
    const int nwaves = (gridDim.x * blockDim.x) >> 6;   // 8192

    const f32x4* __restrict__ c4p = reinterpret_cast<const f32x4*>(c);
    const float4* __restrict__ s4p = reinterpret_cast<const float4*>(s);

    const int sel1 = lane & 1;
    const int sel2 = (lane >> 1) & 1;
    const int sel4 = (lane >> 2) & 1;

    // Iteration i: 8192 waves cover a contiguous 64 MB front sweeping c.
    for (int r0 = gwave * kRowsPerIter; r0 < total_rows;
         r0 += nwaves * kRowsPerIter) {

        const int b = r0 >> kLogN;            // 8 | 8192 -> one batch per octet
        const float4 s4 = s4p[b * kF4PerRow + lane];

        // 8 independent coalesced 1-KiB wave loads, non-temporal
        // (don't allocate in L2/L3 -> don't evict the dirty poison lines)
        f32x4 a[kRowsPerIter];
        #pragma unroll
        for (int u = 0; u < kRowsPerIter; ++u)
            a[u] = __builtin_nontemporal_load(
                &c4p[(size_t)(r0 + u) * kF4PerRow + lane]);

        float p[kRowsPerIter];
        #pragma unroll
        for (int u = 0; u < kRowsPerIter; ++u)
            p[u] = fmaf(a[u].x, s4.x,
                   fmaf(a[u].y, s4.y,
                   fmaf(a[u].z, s4.z, a[u].w * s4.w)));

        // Merge tree: 7 shuffles -> lane l owns row (l&7) summed over octet.
        float v01 = lane_merge(p[0], p[1], sel1, 1);
        float v23 = lane_merge(p[2], p[3], sel1, 1);
        float v45 = lane_merge(p[4], p[5], sel1, 1);
        float v67 = lane_merge(p[6], p[7], sel1, 1);
        float w03 = lane_merge(v01, v23, sel2, 2);
        float w47 = lane_merge(v45, v67, sel2, 2);
        float v   = lane_merge(w03, w47, sel4, 4);

        // Butterfly over remaining lane bits: 3 shuffles.
        v += __shfl_xor(v, 8, 64);
        v += __shfl_xor(v, 16, 64);
        v += __shfl_xor(v, 32, 64);

        // lane l (l<8) holds the total for row r0+l: 32 B coalesced store.
        if (lane < kRowsPerIter)
            out[r0 + lane] = v;
    }
}

extern "C" void kernel_launch(void* const* d_in, const int* in_sizes, int n_in,
                              void* d_out, int out_size, void* d_ws, size_t ws_size,
                              hipStream_t stream) {
    const float* c = (const float*)d_in[0];
    const float* s = (const float*)d_in[1];
    float* out = (float*)d_out;

    ctx_seg_score_kernel<<<kBlocks, kThreads, 0, stream>>>(c, s, out, out_size);
}